// Round 1
// baseline (151.742 us; speedup 1.0000x reference)
//
#include <hip/hip_runtime.h>

#define N_PV 14000
#define N_OLM 12000
#define N_BIST 8000

// -------- kernel A: drive = mean(pv_g_exc), f64 accumulate --------
__global__ __launch_bounds__(1024) void drive_kernel(const float* __restrict__ g,
                                                     float* __restrict__ out) {
    double s = 0.0;
    for (int i = threadIdx.x; i < N_PV; i += 1024) s += (double)g[i];
    for (int off = 32; off > 0; off >>= 1) s += __shfl_down(s, off, 64);
    __shared__ double ls[16];
    const int wid = threadIdx.x >> 6, lane = threadIdx.x & 63;
    if (lane == 0) ls[wid] = s;
    __syncthreads();
    if (threadIdx.x == 0) {
        double S = 0.0;
        for (int k = 0; k < 16; ++k) S += ls[k];
        out[0] = (float)(S / (double)N_PV);
    }
}

// -------- kernel B: per-row sum + dot with pv_V (one block per row) --------
__global__ __launch_bounds__(256) void row_kernel(const float* __restrict__ W,
                                                  const float* __restrict__ V,
                                                  float* __restrict__ rowsum,
                                                  float* __restrict__ rowdot) {
    const int row = blockIdx.x;
    const float4* __restrict__ wr = (const float4*)(W + (size_t)row * N_PV);
    const float4* __restrict__ vv = (const float4*)V;
    double s = 0.0, d = 0.0;
    for (int j = threadIdx.x; j < N_PV / 4; j += 256) {
        const float4 w = wr[j];
        const float4 v = vv[j];
        s += (double)w.x + (double)w.y + (double)w.z + (double)w.w;
        d += (double)w.x * (double)v.x + (double)w.y * (double)v.y
           + (double)w.z * (double)v.z + (double)w.w * (double)v.w;
    }
    for (int off = 32; off > 0; off >>= 1) {
        s += __shfl_down(s, off, 64);
        d += __shfl_down(d, off, 64);
    }
    __shared__ double ls[4], ld[4];
    const int wid = threadIdx.x >> 6, lane = threadIdx.x & 63;
    if (lane == 0) { ls[wid] = s; ld[wid] = d; }
    __syncthreads();
    if (threadIdx.x == 0) {
        const double S = (ls[0] + ls[1]) + (ls[2] + ls[3]);
        const double D = (ld[0] + ld[1]) + (ld[2] + ld[3]);
        rowsum[row] = (float)S;
        rowdot[row] = (float)D;
    }
}

// -------- kernel C: fused LIF step for all three populations --------
__global__ __launch_bounds__(256) void lif_kernel(
    const float* __restrict__ pv_g_exc,  const float* __restrict__ pv_g_inh,
    const float* __restrict__ olm_g_exc, const float* __restrict__ olm_g_inh,
    const float* __restrict__ bi_g_exc,  const float* __restrict__ bi_g_inh,
    const float* __restrict__ pv_V,  const float* __restrict__ pv_tau,
    const float* __restrict__ pv_vth, const float* __restrict__ pv_gL,
    const float* __restrict__ pv_w,
    const float* __restrict__ olm_V,  const float* __restrict__ olm_tau,
    const float* __restrict__ olm_vth, const float* __restrict__ olm_gL,
    const float* __restrict__ olm_w,
    const float* __restrict__ bi_V,  const float* __restrict__ bi_tau,
    const float* __restrict__ bi_vth, const float* __restrict__ bi_gL,
    const float* __restrict__ bi_w,
    const float* __restrict__ rowsum, const float* __restrict__ rowdot,
    const float* __restrict__ drive_p,
    float* __restrict__ out) {
#pragma clang fp contract(off)
    const int i = blockIdx.x * 256 + threadIdx.x;
    const float E_E = 3.0f, E_I = -0.5f, E_NMDA = 3.0f;
    if (i < N_PV) {
        const float drive  = drive_p[0];
        const float gain   = fminf(1.0f, drive / 0.1f);
        const float active = (drive > 0.01f) ? 1.0f : 0.0f;
        const float gt   = rowsum[i];
        const float Egap = rowdot[i] / (gt + 1e-9f);
        const float ggap = gt * gain * active;
        const float V   = pv_V[i];
        const float gex = pv_g_exc[i];
        const float ga  = gex * 0.7f;
        const float gn  = gex * 0.3f;
        const float gi  = pv_g_inh[i];
        const float syn = (ga * (E_E - V) + gn * (E_NMDA - V) + gi * (E_I - V)
                           + ggap * (Egap - V) - pv_w[i]) / pv_gL[i];
        const float Vn = V + (1.0f / pv_tau[i]) * ((0.0f - V) + syn);
        out[i] = (Vn >= pv_vth[i]) ? 1.0f : 0.0f;
    } else if (i < N_PV + N_OLM) {
        const int j = i - N_PV;
        const float V   = olm_V[j];
        const float gex = olm_g_exc[j];
        const float ga  = gex * 0.95f;
        const float gn  = gex * 0.05f;
        const float gi  = olm_g_inh[j];
        const float syn = (ga * (E_E - V) + gn * (E_NMDA - V) + gi * (E_I - V)
                           + 0.0f * (0.0f - V) - olm_w[j]) / olm_gL[j];
        const float Vn = V + (1.0f / olm_tau[j]) * ((0.0f - V) + syn);
        out[i] = (Vn >= olm_vth[j]) ? 1.0f : 0.0f;
    } else if (i < N_PV + N_OLM + N_BIST) {
        const int j = i - N_PV - N_OLM;
        const float V   = bi_V[j];
        const float gex = bi_g_exc[j];
        const float ga  = gex * 0.95f;
        const float gn  = gex * 0.05f;
        const float gi  = bi_g_inh[j];
        const float syn = (ga * (E_E - V) + gn * (E_NMDA - V) + gi * (E_I - V)
                           + 0.0f * (0.0f - V) - bi_w[j]) / bi_gL[j];
        const float Vn = V + (1.0f / bi_tau[j]) * ((0.0f - V) + syn);
        out[i] = (Vn >= bi_vth[j]) ? 1.0f : 0.0f;
    }
}

extern "C" void kernel_launch(void* const* d_in, const int* in_sizes, int n_in,
                              void* d_out, int out_size, void* d_ws, size_t ws_size,
                              hipStream_t stream) {
    const float* pv_g_exc   = (const float*)d_in[0];
    const float* pv_g_inh   = (const float*)d_in[1];
    const float* olm_g_exc  = (const float*)d_in[2];
    const float* olm_g_inh  = (const float*)d_in[3];
    const float* bist_g_exc = (const float*)d_in[4];
    const float* bist_g_inh = (const float*)d_in[5];
    const float* W_gap      = (const float*)d_in[6];
    const float* pv_V       = (const float*)d_in[7];
    const float* pv_tau     = (const float*)d_in[8];
    const float* pv_vth     = (const float*)d_in[9];
    const float* pv_gL      = (const float*)d_in[10];
    // d_in[11] = pv_vreset (unused: only V_out, not spikes, depends on it)
    const float* pv_w       = (const float*)d_in[12];
    const float* olm_V      = (const float*)d_in[13];
    const float* olm_tau    = (const float*)d_in[14];
    const float* olm_vth    = (const float*)d_in[15];
    const float* olm_gL     = (const float*)d_in[16];
    // d_in[17] = olm_vreset (unused)
    const float* olm_w      = (const float*)d_in[18];
    const float* bist_V     = (const float*)d_in[19];
    const float* bist_tau   = (const float*)d_in[20];
    const float* bist_vth   = (const float*)d_in[21];
    const float* bist_gL    = (const float*)d_in[22];
    // d_in[23] = bist_vreset (unused)
    const float* bist_w     = (const float*)d_in[24];

    float* ws      = (float*)d_ws;
    float* rowsum  = ws;              // N_PV floats
    float* rowdot  = ws + N_PV;       // N_PV floats
    float* drive_p = ws + 2 * N_PV;   // 1 float

    hipLaunchKernelGGL(drive_kernel, dim3(1), dim3(1024), 0, stream,
                       pv_g_exc, drive_p);
    hipLaunchKernelGGL(row_kernel, dim3(N_PV), dim3(256), 0, stream,
                       W_gap, pv_V, rowsum, rowdot);
    const int total = N_PV + N_OLM + N_BIST;
    hipLaunchKernelGGL(lif_kernel, dim3((total + 255) / 256), dim3(256), 0, stream,
                       pv_g_exc, pv_g_inh, olm_g_exc, olm_g_inh,
                       bist_g_exc, bist_g_inh,
                       pv_V, pv_tau, pv_vth, pv_gL, pv_w,
                       olm_V, olm_tau, olm_vth, olm_gL, olm_w,
                       bist_V, bist_tau, bist_vth, bist_gL, bist_w,
                       rowsum, rowdot, drive_p,
                       (float*)d_out);
}

// Round 3
// 142.257 us; speedup vs baseline: 1.0667x; 1.0667x over previous
//
#include <hip/hip_runtime.h>

#define N_PV 14000
#define N_OLM 12000
#define N_BIST 8000
#define NVEC (N_PV / 4)   // 3500 float4 per row

typedef float f32x4 __attribute__((ext_vector_type(4)));

// -------- kernel B+A fused: per-row sum + dot with pv_V (one block per row);
//          block N_PV computes drive = mean(pv_g_exc) --------
__global__ __launch_bounds__(256) void row_kernel(const float* __restrict__ W,
                                                  const float* __restrict__ V,
                                                  const float* __restrict__ pv_g_exc,
                                                  float* __restrict__ rowsum,
                                                  float* __restrict__ rowdot,
                                                  float* __restrict__ drive_p) {
    __shared__ double ls[4], ld[4];
    const int wid = threadIdx.x >> 6, lane = threadIdx.x & 63;
    const int row = blockIdx.x;

    if (row == N_PV) {
        // drive = mean(pv_g_exc), f64 accumulate
        double s = 0.0;
        for (int i = threadIdx.x; i < N_PV; i += 256) s += (double)pv_g_exc[i];
        for (int off = 32; off > 0; off >>= 1) s += __shfl_down(s, off, 64);
        if (lane == 0) ls[wid] = s;
        __syncthreads();
        if (threadIdx.x == 0)
            drive_p[0] = (float)(((ls[0] + ls[1]) + (ls[2] + ls[3])) / (double)N_PV);
        return;
    }

    const f32x4* __restrict__ wr = (const f32x4*)(W + (size_t)row * N_PV);
    const f32x4* __restrict__ vv = (const f32x4*)V;
    double s0 = 0.0, d0 = 0.0, s1 = 0.0, d1 = 0.0;
    int j = threadIdx.x;
    // 2-deep unroll: two independent load chains in flight per thread
    for (; j + 256 < NVEC; j += 512) {
        const f32x4 w0 = __builtin_nontemporal_load(&wr[j]);
        const f32x4 v0 = vv[j];
        const f32x4 w1 = __builtin_nontemporal_load(&wr[j + 256]);
        const f32x4 v1 = vv[j + 256];
        s0 += (double)w0.x + (double)w0.y + (double)w0.z + (double)w0.w;
        d0 += (double)w0.x * (double)v0.x + (double)w0.y * (double)v0.y
            + (double)w0.z * (double)v0.z + (double)w0.w * (double)v0.w;
        s1 += (double)w1.x + (double)w1.y + (double)w1.z + (double)w1.w;
        d1 += (double)w1.x * (double)v1.x + (double)w1.y * (double)v1.y
            + (double)w1.z * (double)v1.z + (double)w1.w * (double)v1.w;
    }
    for (; j < NVEC; j += 256) {
        const f32x4 w0 = __builtin_nontemporal_load(&wr[j]);
        const f32x4 v0 = vv[j];
        s0 += (double)w0.x + (double)w0.y + (double)w0.z + (double)w0.w;
        d0 += (double)w0.x * (double)v0.x + (double)w0.y * (double)v0.y
            + (double)w0.z * (double)v0.z + (double)w0.w * (double)v0.w;
    }
    double s = s0 + s1, d = d0 + d1;
    for (int off = 32; off > 0; off >>= 1) {
        s += __shfl_down(s, off, 64);
        d += __shfl_down(d, off, 64);
    }
    if (lane == 0) { ls[wid] = s; ld[wid] = d; }
    __syncthreads();
    if (threadIdx.x == 0) {
        rowsum[row] = (float)((ls[0] + ls[1]) + (ls[2] + ls[3]));
        rowdot[row] = (float)((ld[0] + ld[1]) + (ld[2] + ld[3]));
    }
}

// -------- kernel C: fused LIF step for all three populations --------
__global__ __launch_bounds__(256) void lif_kernel(
    const float* __restrict__ pv_g_exc,  const float* __restrict__ pv_g_inh,
    const float* __restrict__ olm_g_exc, const float* __restrict__ olm_g_inh,
    const float* __restrict__ bi_g_exc,  const float* __restrict__ bi_g_inh,
    const float* __restrict__ pv_V,  const float* __restrict__ pv_tau,
    const float* __restrict__ pv_vth, const float* __restrict__ pv_gL,
    const float* __restrict__ pv_w,
    const float* __restrict__ olm_V,  const float* __restrict__ olm_tau,
    const float* __restrict__ olm_vth, const float* __restrict__ olm_gL,
    const float* __restrict__ olm_w,
    const float* __restrict__ bi_V,  const float* __restrict__ bi_tau,
    const float* __restrict__ bi_vth, const float* __restrict__ bi_gL,
    const float* __restrict__ bi_w,
    const float* __restrict__ rowsum, const float* __restrict__ rowdot,
    const float* __restrict__ drive_p,
    float* __restrict__ out) {
#pragma clang fp contract(off)
    const int i = blockIdx.x * 256 + threadIdx.x;
    const float E_E = 3.0f, E_I = -0.5f, E_NMDA = 3.0f;
    if (i < N_PV) {
        const float drive  = drive_p[0];
        const float gain   = fminf(1.0f, drive / 0.1f);
        const float active = (drive > 0.01f) ? 1.0f : 0.0f;
        const float gt   = rowsum[i];
        const float Egap = rowdot[i] / (gt + 1e-9f);
        const float ggap = gt * gain * active;
        const float V   = pv_V[i];
        const float gex = pv_g_exc[i];
        const float ga  = gex * 0.7f;
        const float gn  = gex * 0.3f;
        const float gi  = pv_g_inh[i];
        const float syn = (ga * (E_E - V) + gn * (E_NMDA - V) + gi * (E_I - V)
                           + ggap * (Egap - V) - pv_w[i]) / pv_gL[i];
        const float Vn = V + (1.0f / pv_tau[i]) * ((0.0f - V) + syn);
        out[i] = (Vn >= pv_vth[i]) ? 1.0f : 0.0f;
    } else if (i < N_PV + N_OLM) {
        const int j = i - N_PV;
        const float V   = olm_V[j];
        const float gex = olm_g_exc[j];
        const float ga  = gex * 0.95f;
        const float gn  = gex * 0.05f;
        const float gi  = olm_g_inh[j];
        const float syn = (ga * (E_E - V) + gn * (E_NMDA - V) + gi * (E_I - V)
                           + 0.0f * (0.0f - V) - olm_w[j]) / olm_gL[j];
        const float Vn = V + (1.0f / olm_tau[j]) * ((0.0f - V) + syn);
        out[i] = (Vn >= olm_vth[j]) ? 1.0f : 0.0f;
    } else if (i < N_PV + N_OLM + N_BIST) {
        const int j = i - N_PV - N_OLM;
        const float V   = bi_V[j];
        const float gex = bi_g_exc[j];
        const float ga  = gex * 0.95f;
        const float gn  = gex * 0.05f;
        const float gi  = bi_g_inh[j];
        const float syn = (ga * (E_E - V) + gn * (E_NMDA - V) + gi * (E_I - V)
                           + 0.0f * (0.0f - V) - bi_w[j]) / bi_gL[j];
        const float Vn = V + (1.0f / bi_tau[j]) * ((0.0f - V) + syn);
        out[i] = (Vn >= bi_vth[j]) ? 1.0f : 0.0f;
    }
}

extern "C" void kernel_launch(void* const* d_in, const int* in_sizes, int n_in,
                              void* d_out, int out_size, void* d_ws, size_t ws_size,
                              hipStream_t stream) {
    const float* pv_g_exc   = (const float*)d_in[0];
    const float* pv_g_inh   = (const float*)d_in[1];
    const float* olm_g_exc  = (const float*)d_in[2];
    const float* olm_g_inh  = (const float*)d_in[3];
    const float* bist_g_exc = (const float*)d_in[4];
    const float* bist_g_inh = (const float*)d_in[5];
    const float* W_gap      = (const float*)d_in[6];
    const float* pv_V       = (const float*)d_in[7];
    const float* pv_tau     = (const float*)d_in[8];
    const float* pv_vth     = (const float*)d_in[9];
    const float* pv_gL      = (const float*)d_in[10];
    // d_in[11] = pv_vreset (unused: spikes don't depend on it)
    const float* pv_w       = (const float*)d_in[12];
    const float* olm_V      = (const float*)d_in[13];
    const float* olm_tau    = (const float*)d_in[14];
    const float* olm_vth    = (const float*)d_in[15];
    const float* olm_gL     = (const float*)d_in[16];
    // d_in[17] = olm_vreset (unused)
    const float* olm_w      = (const float*)d_in[18];
    const float* bist_V     = (const float*)d_in[19];
    const float* bist_tau   = (const float*)d_in[20];
    const float* bist_vth   = (const float*)d_in[21];
    const float* bist_gL    = (const float*)d_in[22];
    // d_in[23] = bist_vreset (unused)
    const float* bist_w     = (const float*)d_in[24];

    float* ws      = (float*)d_ws;
    float* rowsum  = ws;              // N_PV floats
    float* rowdot  = ws + N_PV;       // N_PV floats
    float* drive_p = ws + 2 * N_PV;   // 1 float

    hipLaunchKernelGGL(row_kernel, dim3(N_PV + 1), dim3(256), 0, stream,
                       W_gap, pv_V, pv_g_exc, rowsum, rowdot, drive_p);
    const int total = N_PV + N_OLM + N_BIST;
    hipLaunchKernelGGL(lif_kernel, dim3((total + 255) / 256), dim3(256), 0, stream,
                       pv_g_exc, pv_g_inh, olm_g_exc, olm_g_inh,
                       bist_g_exc, bist_g_inh,
                       pv_V, pv_tau, pv_vth, pv_gL, pv_w,
                       olm_V, olm_tau, olm_vth, olm_gL, olm_w,
                       bist_V, bist_tau, bist_vth, bist_gL, bist_w,
                       rowsum, rowdot, drive_p,
                       (float*)d_out);
}